// Round 1
// baseline (540.247 us; speedup 1.0000x reference)
//
#include <hip/hip_runtime.h>
#include <stdint.h>

#define EMB 128

typedef unsigned short ushort_t;
typedef ushort_t us8 __attribute__((ext_vector_type(8)));
typedef float f4 __attribute__((ext_vector_type(4)));

static __device__ __forceinline__ float bf2f(ushort_t h) {
    union { unsigned int u; float f; } cvt;
    cvt.u = ((unsigned int)h) << 16;
    return cvt.f;
}

static __device__ __forceinline__ ushort_t f2bf(float f) {
    union { float f; unsigned int u; } cvt;
    cvt.f = f;
    unsigned int u = cvt.u;
    unsigned int r = u + 0x7fffu + ((u >> 16) & 1u);
    return (ushort_t)(r >> 16);
}

// ---------------------------------------------------------------------------
// Primary path: fused  W fp32 [EMB][VOCAB] + b  ->  N fp32 [VOCAB][EMB]
// where N[v] = normalize(W[:,v] + b).  Norm depends only on v, so compute it
// ONCE per vocab row here instead of once per token (8.2x redundancy removed).
// ---------------------------------------------------------------------------
__global__ __launch_bounds__(256) void build_table_f32_kernel(
    const float* __restrict__ W, const float* __restrict__ b,
    float* __restrict__ N, int vocab)
{
    __shared__ float tile[EMB][33];   // [e][v-in-tile], padded: 16.9 KB
    __shared__ float part[8][32];
    __shared__ float scale_s[32];

    const int v0 = blockIdx.x * 32;
    const int tx = threadIdx.x;       // 0..31 : vocab within tile
    const int ty = threadIdx.y;       // 0..7

    const int v  = v0 + tx;
    const bool vok = (v < vocab);

    // Phase 1: load 128 x 32 tile of W (coalesced along vocab) + bias add.
    #pragma unroll
    for (int e = ty; e < EMB; e += 8) {
        float w = vok ? W[(size_t)e * vocab + v] : 0.0f;
        tile[e][tx] = w + b[e];
    }
    __syncthreads();

    // Phase 2: per-column partial sum of squares (16 e-values per thread).
    float ss = 0.0f;
    #pragma unroll
    for (int j = 0; j < 16; ++j) {
        float t = tile[ty * 16 + j][tx];
        ss += t * t;
    }
    part[ty][tx] = ss;
    __syncthreads();

    // Phase 3: finalize 1/max(||.||, eps) per column.
    if (ty == 0) {
        float s = 0.0f;
        #pragma unroll
        for (int j = 0; j < 8; ++j) s += part[j][tx];
        scale_s[tx] = 1.0f / fmaxf(sqrtf(s), 1e-12f);
    }
    __syncthreads();

    // Phase 4: write N rows, f4-vectorized; 32 consecutive threads emit one
    // full 512B row -> fully coalesced stores.
    const int tid = ty * 32 + tx;
    #pragma unroll
    for (int c = 0; c < 4; ++c) {
        const int chunk = tid + c * 256;  // 0..1023 = 32 rows x 32 f4-chunks
        const int r = chunk >> 5;         // row in tile (vocab)
        const int q = chunk & 31;         // f4 index within row (emb/4)
        const int vv = v0 + r;
        if (vv < vocab) {
            const float sc = scale_s[r];
            f4 o;
            #pragma unroll
            for (int j = 0; j < 4; ++j) o[j] = tile[q * 4 + j][r] * sc;
            *(f4*)(N + (size_t)vv * EMB + q * 4) = o;
        }
    }
}

// Detect int64 vs int32 indices: all high words of first 64 entries zero -> int64.
static __device__ __forceinline__ int detect_i64(const int* __restrict__ x32) {
    __shared__ int is64_s;
    if (threadIdx.x < 64) {
        int w = x32[2 * threadIdx.x + 1];
        unsigned long long nz = __ballot(w != 0);
        if (threadIdx.x == 0) is64_s = (nz == 0ULL) ? 1 : 0;
    }
    __syncthreads();
    return is64_s;
}

// ---------------------------------------------------------------------------
// Primary gather: pure row copy, 16 lanes/token, 32B/lane.
// Non-temporal stores keep the 51.2MB table L3-resident (output is 419MB of
// write-once data that must not evict it).
// ---------------------------------------------------------------------------
__global__ __launch_bounds__(256) void gather_copy_f32_kernel(
    const int* __restrict__ x, const float* __restrict__ N,
    float* __restrict__ out, int n_tokens, int vocab)
{
    const int is64 = detect_i64(x);
    const int tid   = blockIdx.x * blockDim.x + threadIdx.x;
    const int token = tid >> 4;
    const int l     = tid & 15;
    if (token >= n_tokens) return;

    int v = is64 ? x[2 * token] : x[token];
    v = min(max(v, 0), vocab - 1);

    const float* src = N + (size_t)v * EMB + l * 8;
    f4 a = *(const f4*)src;
    f4 c = *(const f4*)(src + 4);

    float* dst = out + (size_t)token * EMB + l * 8;
    __builtin_nontemporal_store(a, (f4*)dst);
    __builtin_nontemporal_store(c, (f4*)(dst + 4));
}

// ---------------------------------------------------------------------------
// Fallback paths (unchanged from verified kernel): bf16 table / direct gather
// ---------------------------------------------------------------------------
__global__ __launch_bounds__(256) void transpose_bf16_kernel(
    const float* __restrict__ W, ushort_t* __restrict__ Wt, int vocab)
{
    __shared__ float tile[32][33];
    const int v0 = blockIdx.x * 32;
    const int e0 = blockIdx.y * 32;
    const int tx = threadIdx.x;
    const int ty = threadIdx.y;

    #pragma unroll
    for (int i = 0; i < 32; i += 8) {
        int e = e0 + ty + i;
        int v = v0 + tx;
        if (e < EMB && v < vocab)
            tile[ty + i][tx] = W[(size_t)e * vocab + v];
    }
    __syncthreads();
    #pragma unroll
    for (int i = 0; i < 32; i += 8) {
        int v = v0 + ty + i;
        int e = e0 + tx;
        if (v < vocab && e < EMB)
            Wt[(size_t)v * EMB + e] = f2bf(tile[tx][ty + i]);
    }
}

static __device__ __forceinline__ void reduce_norm_store(
    float e[8], float* __restrict__ out, int token, int l)
{
    float ss = 0.0f;
    #pragma unroll
    for (int j = 0; j < 8; ++j) ss += e[j] * e[j];
    #pragma unroll
    for (int m = 1; m < 16; m <<= 1)
        ss += __shfl_xor(ss, m, 16);
    const float n = sqrtf(ss);
    const float scale = 1.0f / fmaxf(n, 1e-12f);

    f4 o0, o1;
    #pragma unroll
    for (int j = 0; j < 4; ++j) { o0[j] = e[j] * scale; o1[j] = e[j + 4] * scale; }
    float* dst = out + (size_t)token * EMB + l * 8;
    *(f4*)dst = o0;
    *(f4*)(dst + 4) = o1;
}

__global__ __launch_bounds__(256) void gather_norm_bf16_kernel(
    const int* __restrict__ x, const ushort_t* __restrict__ Wt,
    const float* __restrict__ b, float* __restrict__ out,
    int n_tokens, int vocab)
{
    const int is64 = detect_i64(x);
    const int tid   = blockIdx.x * blockDim.x + threadIdx.x;
    const int token = tid >> 4;
    const int l     = tid & 15;
    if (token >= n_tokens) return;

    int v = is64 ? x[2 * token] : x[token];
    v = min(max(v, 0), vocab - 1);

    us8 w  = *(const us8*)(Wt + (size_t)v * EMB + l * 8);
    f4 b0  = *(const f4*)(b + l * 8);
    f4 b1  = *(const f4*)(b + l * 8 + 4);

    float e[8];
    #pragma unroll
    for (int j = 0; j < 4; ++j) {
        e[j]     = bf2f(w[j])     + b0[j];
        e[j + 4] = bf2f(w[j + 4]) + b1[j];
    }
    reduce_norm_store(e, out, token, l);
}

__global__ __launch_bounds__(256) void gather_norm_direct_kernel(
    const int* __restrict__ x, const float* __restrict__ W,
    const float* __restrict__ b, float* __restrict__ out,
    int n_tokens, int vocab)
{
    const int is64 = detect_i64(x);
    const int tid   = blockIdx.x * blockDim.x + threadIdx.x;
    const int token = tid >> 4;
    const int l     = tid & 15;
    if (token >= n_tokens) return;

    int v = is64 ? x[2 * token] : x[token];
    v = min(max(v, 0), vocab - 1);

    f4 b0 = *(const f4*)(b + l * 8);
    f4 b1 = *(const f4*)(b + l * 8 + 4);

    float e[8];
    #pragma unroll
    for (int j = 0; j < 8; ++j) {
        float w = W[(size_t)(l * 8 + j) * vocab + v];
        float bj = (j < 4) ? b0[j & 3] : b1[j & 3];
        e[j] = w + bj;
    }
    reduce_norm_store(e, out, token, l);
}

extern "C" void kernel_launch(void* const* d_in, const int* in_sizes, int n_in,
                              void* d_out, int out_size, void* d_ws, size_t ws_size,
                              hipStream_t stream) {
    const int*   x = (const int*)d_in[0];
    const float* W = (const float*)d_in[1];
    const float* b = (const float*)d_in[2];
    float*     out = (float*)d_out;

    const int n_tokens = in_sizes[0];            // 4096*200 = 819200
    const int vocab    = in_sizes[1] / EMB;      // 100000

    const size_t wt_f32_bytes  = (size_t)vocab * EMB * sizeof(float);     // 51.2 MB
    const size_t wt_bf16_bytes = (size_t)vocab * EMB * sizeof(ushort_t);  // 25.6 MB
    const int blocks = (n_tokens * 16 + 255) / 256;                       // 16 lanes/token

    if (ws_size >= wt_f32_bytes) {
        float* N = (float*)d_ws;
        build_table_f32_kernel<<<dim3((vocab + 31) / 32), dim3(32, 8), 0, stream>>>(
            W, b, N, vocab);
        gather_copy_f32_kernel<<<blocks, 256, 0, stream>>>(x, N, out, n_tokens, vocab);
    } else if (ws_size >= wt_bf16_bytes) {
        ushort_t* Wt = (ushort_t*)d_ws;
        dim3 tb(32, 8);
        dim3 tg((vocab + 31) / 32, (EMB + 31) / 32);
        transpose_bf16_kernel<<<tg, tb, 0, stream>>>(W, Wt, vocab);
        gather_norm_bf16_kernel<<<blocks, 256, 0, stream>>>(x, Wt, b, out, n_tokens, vocab);
    } else {
        gather_norm_direct_kernel<<<blocks, 256, 0, stream>>>(x, W, b, out, n_tokens, vocab);
    }
}

// Round 2
// 479.921 us; speedup vs baseline: 1.1257x; 1.1257x over previous
//
#include <hip/hip_runtime.h>
#include <stdint.h>

#define EMB 128

typedef unsigned short ushort_t;
typedef _Float16 half_t;
typedef half_t h8 __attribute__((ext_vector_type(8)));
typedef float f4 __attribute__((ext_vector_type(4)));

// ---------------------------------------------------------------------------
// Fused table build:  W fp32 [EMB][VOCAB] + b  ->  T fp16 [VOCAB][EMB]
// T[v] = fp16( normalize(W[:,v] + b) ).  Norm depends only on v, so it is
// computed ONCE per vocab row (100K rows) instead of once per token (819K).
// fp16 is safe: |normalized elem| <= 1 always (|e_j| <= ||e||, and the
// n<eps branch yields |e_j/eps| <= 1 too). fp16 rel err 2^-11 beats the
// previously-passing bf16 path's 2^-9.
// Table = 25.6 MB -> fits the [25.6, 51.2) MB workspace AND is ~L2-scale.
// ---------------------------------------------------------------------------
__global__ __launch_bounds__(256) void build_table_f16_kernel(
    const float* __restrict__ W, const float* __restrict__ b,
    half_t* __restrict__ T, int vocab)
{
    __shared__ float tile[EMB][33];   // [e][v-in-tile], padded
    __shared__ float part[8][32];
    __shared__ float scale_s[32];

    const int v0 = blockIdx.x * 32;
    const int tx = threadIdx.x;       // 0..31 : vocab within tile
    const int ty = threadIdx.y;       // 0..7

    const int v  = v0 + tx;
    const bool vok = (v < vocab);

    // Phase 1: load 128 x 32 tile of W (coalesced along vocab) + bias add.
    #pragma unroll
    for (int e = ty; e < EMB; e += 8) {
        float w = vok ? W[(size_t)e * vocab + v] : 0.0f;
        tile[e][tx] = w + b[e];
    }
    __syncthreads();

    // Phase 2: per-column partial sum of squares (16 e-values per thread).
    float ss = 0.0f;
    #pragma unroll
    for (int j = 0; j < 16; ++j) {
        float t = tile[ty * 16 + j][tx];
        ss += t * t;
    }
    part[ty][tx] = ss;
    __syncthreads();

    // Phase 3: finalize 1/max(||.||, eps) per column.
    if (ty == 0) {
        float s = 0.0f;
        #pragma unroll
        for (int j = 0; j < 8; ++j) s += part[j][tx];
        scale_s[tx] = 1.0f / fmaxf(sqrtf(s), 1e-12f);
    }
    __syncthreads();

    // Phase 4: write T rows as fp16, 16B chunks; 16 consecutive threads emit
    // one full 256B row -> fully coalesced stores. 512 chunks, 2 per thread.
    const int tid = ty * 32 + tx;
    #pragma unroll
    for (int c = 0; c < 2; ++c) {
        const int chunk = tid + c * 256;  // 0..511 = 32 rows x 16 h8-chunks
        const int r = chunk >> 4;         // row in tile (vocab)
        const int q = chunk & 15;         // h8 index within row
        const int vv = v0 + r;
        if (vv < vocab) {
            const float sc = scale_s[r];
            h8 o;
            #pragma unroll
            for (int j = 0; j < 8; ++j)
                o[j] = (half_t)(tile[q * 8 + j][r] * sc);
            *(h8*)(T + (size_t)vv * EMB + q * 8) = o;
        }
    }
}

// Detect int64 vs int32 indices: all high words of first 64 entries zero -> int64.
static __device__ __forceinline__ int detect_i64(const int* __restrict__ x32) {
    __shared__ int is64_s;
    if (threadIdx.x < 64) {
        int w = x32[2 * threadIdx.x + 1];
        unsigned long long nz = __ballot(w != 0);
        if (threadIdx.x == 0) is64_s = (nz == 0ULL) ? 1 : 0;
    }
    __syncthreads();
    return is64_s;
}

// ---------------------------------------------------------------------------
// Gather: pure row copy + fp16->fp32 widen. 16 lanes/token, 16B read +
// 32B nt-write per lane. Each thread handles TWO independent tokens
// (t and t+half) to double outstanding random row reads (MLP).
// nt stores keep the 419MB write-once output from evicting the table.
// ---------------------------------------------------------------------------
__global__ __launch_bounds__(256) void gather_copy_f16_kernel(
    const int* __restrict__ x, const half_t* __restrict__ T,
    float* __restrict__ out, int n_tokens, int vocab)
{
    const int is64 = detect_i64(x);
    const int half_n = (n_tokens + 1) >> 1;
    const int tid = blockIdx.x * blockDim.x + threadIdx.x;
    const int t0  = tid >> 4;
    const int l   = tid & 15;
    if (t0 >= half_n) return;

    const int t1  = t0 + half_n;
    const int t1c = min(t1, n_tokens - 1);

    int v0i = is64 ? x[2 * t0]  : x[t0];
    int v1i = is64 ? x[2 * t1c] : x[t1c];
    v0i = min(max(v0i, 0), vocab - 1);
    v1i = min(max(v1i, 0), vocab - 1);

    const h8 w0 = *(const h8*)(T + (size_t)v0i * EMB + l * 8);
    const h8 w1 = *(const h8*)(T + (size_t)v1i * EMB + l * 8);

    f4 a0, c0, a1, c1;
    #pragma unroll
    for (int j = 0; j < 4; ++j) {
        a0[j] = (float)w0[j];  c0[j] = (float)w0[j + 4];
        a1[j] = (float)w1[j];  c1[j] = (float)w1[j + 4];
    }

    float* d0 = out + (size_t)t0 * EMB + l * 8;
    __builtin_nontemporal_store(a0, (f4*)d0);
    __builtin_nontemporal_store(c0, (f4*)(d0 + 4));

    if (t1 < n_tokens) {
        float* d1 = out + (size_t)t1 * EMB + l * 8;
        __builtin_nontemporal_store(a1, (f4*)d1);
        __builtin_nontemporal_store(c1, (f4*)(d1 + 4));
    }
}

// ---------------------------------------------------------------------------
// Last-resort fallback (ws too small for any table): direct column gather.
// ---------------------------------------------------------------------------
static __device__ __forceinline__ void reduce_norm_store(
    float e[8], float* __restrict__ out, int token, int l)
{
    float ss = 0.0f;
    #pragma unroll
    for (int j = 0; j < 8; ++j) ss += e[j] * e[j];
    #pragma unroll
    for (int m = 1; m < 16; m <<= 1)
        ss += __shfl_xor(ss, m, 16);
    const float n = sqrtf(ss);
    const float scale = 1.0f / fmaxf(n, 1e-12f);

    f4 o0, o1;
    #pragma unroll
    for (int j = 0; j < 4; ++j) { o0[j] = e[j] * scale; o1[j] = e[j + 4] * scale; }
    float* dst = out + (size_t)token * EMB + l * 8;
    *(f4*)dst = o0;
    *(f4*)(dst + 4) = o1;
}

__global__ __launch_bounds__(256) void gather_norm_direct_kernel(
    const int* __restrict__ x, const float* __restrict__ W,
    const float* __restrict__ b, float* __restrict__ out,
    int n_tokens, int vocab)
{
    const int is64 = detect_i64(x);
    const int tid   = blockIdx.x * blockDim.x + threadIdx.x;
    const int token = tid >> 4;
    const int l     = tid & 15;
    if (token >= n_tokens) return;

    int v = is64 ? x[2 * token] : x[token];
    v = min(max(v, 0), vocab - 1);

    f4 b0 = *(const f4*)(b + l * 8);
    f4 b1 = *(const f4*)(b + l * 8 + 4);

    float e[8];
    #pragma unroll
    for (int j = 0; j < 8; ++j) {
        float w = W[(size_t)(l * 8 + j) * vocab + v];
        float bj = (j < 4) ? b0[j & 3] : b1[j & 3];
        e[j] = w + bj;
    }
    reduce_norm_store(e, out, token, l);
}

extern "C" void kernel_launch(void* const* d_in, const int* in_sizes, int n_in,
                              void* d_out, int out_size, void* d_ws, size_t ws_size,
                              hipStream_t stream) {
    const int*   x = (const int*)d_in[0];
    const float* W = (const float*)d_in[1];
    const float* b = (const float*)d_in[2];
    float*     out = (float*)d_out;

    const int n_tokens = in_sizes[0];            // 4096*200 = 819200
    const int vocab    = in_sizes[1] / EMB;      // 100000

    const size_t t_f16_bytes = (size_t)vocab * EMB * sizeof(half_t);  // 25.6 MB

    if (ws_size >= t_f16_bytes) {
        half_t* T = (half_t*)d_ws;
        build_table_f16_kernel<<<dim3((vocab + 31) / 32), dim3(32, 8), 0, stream>>>(
            W, b, T, vocab);
        const int half_n = (n_tokens + 1) >> 1;
        const int blocks = (half_n * 16 + 255) / 256;   // 16 lanes/token, 2 tokens/thread
        gather_copy_f16_kernel<<<blocks, 256, 0, stream>>>(x, T, out, n_tokens, vocab);
    } else {
        const int blocks = (n_tokens * 16 + 255) / 256;
        gather_norm_direct_kernel<<<blocks, 256, 0, stream>>>(x, W, b, out, n_tokens, vocab);
    }
}